// Round 2
// baseline (67.714 us; speedup 1.0000x reference)
//
#include <hip/hip_runtime.h>

#define B   32
#define V   1024
#define HID 768
#define OUT 256

// Kernel 1: c[b][w] = sum_v adj[b][v][w], no atomics.
// grid (B, 16): block owns a 64-wide w-slice, loops ALL 1024 v.
// 256 threads = (4 v-offsets) x (64 w): each wave reads 256B contiguous per iter.
// Blocks with wc<3 also zero h[b][...] (kernel 2 is stream-ordered after us).
__global__ void colsum_kernel(const float* __restrict__ adj,
                              float* __restrict__ c,
                              float* __restrict__ h) {
    const int b  = blockIdx.x;
    const int wc = blockIdx.y;
    const int t  = threadIdx.x;
    const int wi = t & 63;
    const int vo = t >> 6;              // 0..3
    const float* base = adj + (size_t)b * V * V + wc * 64 + wi;
    float acc = 0.f;
    #pragma unroll 8
    for (int v = vo; v < V; v += 4)
        acc += base[(size_t)v * V];
    __shared__ float sm[4][64];
    sm[vo][wi] = acc;
    __syncthreads();
    if (t < 64)
        c[b * V + wc * 64 + t] = sm[0][t] + sm[1][t] + sm[2][t] + sm[3][t];
    if (wc < 3)
        h[b * HID + wc * 256 + t] = 0.f;
}

// Kernel 2: h[b][k] += sum_w c[b][w] * emb[ids[b][w]][k]
// grid (B, 32): block owns 32 w's; 192 threads x float4 = 768 floats = full HID row.
__global__ void gather_wsum_kernel(const float* __restrict__ emb,
                                   const int* __restrict__ ids,
                                   const float* __restrict__ c,
                                   float* __restrict__ h) {
    const int b  = blockIdx.x;
    const int wc = blockIdx.y;
    const int t  = threadIdx.x;         // 0..191
    __shared__ int   ids_s[32];
    __shared__ float c_s[32];
    if (t < 32) {
        ids_s[t] = ids[b * V + wc * 32 + t];
        c_s[t]   = c[b * V + wc * 32 + t];
    }
    __syncthreads();
    float4 acc = make_float4(0.f, 0.f, 0.f, 0.f);
    #pragma unroll 4
    for (int i = 0; i < 32; ++i) {
        const float4* T4 = reinterpret_cast<const float4*>(emb + (size_t)ids_s[i] * HID);
        const float4 a = T4[t];
        const float  s = c_s[i];
        acc.x += s * a.x; acc.y += s * a.y; acc.z += s * a.z; acc.w += s * a.w;
    }
    float* hb = h + b * HID + t * 4;
    atomicAdd(hb + 0, acc.x);
    atomicAdd(hb + 1, acc.y);
    atomicAdd(hb + 2, acc.z);
    atomicAdd(hb + 3, acc.w);
}

// Kernel 3: out[b][o] = fc_b[o] + (1/V) * dot(h[b][:], fc_w[o][:])
// grid (B, OUT/4): 4 waves per block, one output per wave, shuffle reduce.
__global__ void fc_kernel(const float* __restrict__ h,
                          const float* __restrict__ fc_w,
                          const float* __restrict__ fc_b,
                          float* __restrict__ out) {
    const int b    = blockIdx.x;
    const int wave = threadIdx.x >> 6;
    const int lane = threadIdx.x & 63;
    const int o    = blockIdx.y * 4 + wave;
    __shared__ float h_s[HID];
    for (int i = threadIdx.x; i < HID; i += 256) h_s[i] = h[b * HID + i];
    __syncthreads();
    const float* wrow = fc_w + (size_t)o * HID;
    float acc = 0.f;
    #pragma unroll
    for (int k = 0; k < HID / 64; ++k)
        acc += wrow[k * 64 + lane] * h_s[k * 64 + lane];
    #pragma unroll
    for (int off = 32; off > 0; off >>= 1)
        acc += __shfl_down(acc, off, 64);
    if (lane == 0)
        out[b * OUT + o] = fc_b[o] + acc * (1.0f / V);
}

extern "C" void kernel_launch(void* const* d_in, const int* in_sizes, int n_in,
                              void* d_out, int out_size, void* d_ws, size_t ws_size,
                              hipStream_t stream) {
    const float* emb  = (const float*)d_in[0];
    const float* adj  = (const float*)d_in[1];
    const float* fc_w = (const float*)d_in[2];
    const float* fc_b = (const float*)d_in[3];
    const int*   ids  = (const int*)d_in[4];
    float* out = (float*)d_out;

    float* c = (float*)d_ws;          // [B][V]   = 32768 floats
    float* h = c + B * V;             // [B][HID] = 24576 floats (zeroed by kernel 1)

    colsum_kernel<<<dim3(B, 16), 256, 0, stream>>>(adj, c, h);
    gather_wsum_kernel<<<dim3(B, 32), 192, 0, stream>>>(emb, ids, c, h);
    fc_kernel<<<dim3(B, OUT / 4), 256, 0, stream>>>(h, fc_w, fc_b, out);
}

// Round 3
// 54.023 us; speedup vs baseline: 1.2534x; 1.2534x over previous
//
#include <hip/hip_runtime.h>

#define B   32
#define V   1024
#define HID 768
#define OUT 256
#define NVC 16   // v-chunks in colsum

// ---------------- Path A: partial-buffer (no atomics for c, no memset) ----

// Kernel 1A: partial[b][vc][w] = sum over 64 v-rows of adj[b][v][w].
// grid (B, NVC), 256 threads, float4/lane -> 4KB contiguous per block-iter
// (row-buffer friendly, identical pattern to the 59.8us round-0 kernel).
// Blocks with vc<3 also zero h[b][...] (kernel 2 is stream-ordered after us).
__global__ void colsum_partial_kernel(const float* __restrict__ adj,
                                      float* __restrict__ partial,
                                      float* __restrict__ h) {
    const int b   = blockIdx.x;
    const int vc  = blockIdx.y;
    const int tid = threadIdx.x;
    const float4* adj4 = reinterpret_cast<const float4*>(adj)
                       + (size_t)(b * V + vc * 64) * (V / 4);
    float4 acc = make_float4(0.f, 0.f, 0.f, 0.f);
    #pragma unroll 4
    for (int v = 0; v < 64; ++v) {
        float4 a = adj4[(size_t)v * (V / 4) + tid];
        acc.x += a.x; acc.y += a.y; acc.z += a.z; acc.w += a.w;
    }
    reinterpret_cast<float4*>(partial + (size_t)(b * NVC + vc) * V)[tid] = acc;
    if (vc < 3)
        h[b * HID + vc * 256 + tid] = 0.f;
}

// Kernel 2A: h[b][k] += sum_w c[b][w] * emb[ids[b][w]][k],
// where c[b][w] = sum_vc partial[b][vc][w] (reduced in prologue, L2-resident).
// grid (B, 32), 192 threads: float4/lane covers a full HID=768 row.
__global__ void gather_wsum_kernel(const float* __restrict__ emb,
                                   const int* __restrict__ ids,
                                   const float* __restrict__ partial,
                                   float* __restrict__ h) {
    const int b  = blockIdx.x;
    const int wc = blockIdx.y;
    const int t  = threadIdx.x;         // 0..191
    __shared__ float sm[4][32];
    __shared__ float c_s[32];
    __shared__ int   ids_s[32];
    if (t < 128) {
        const int wi = t & 31, q = t >> 5;
        float s = 0.f;
        #pragma unroll
        for (int j = 0; j < 4; ++j)
            s += partial[(size_t)(b * NVC + q * 4 + j) * V + wc * 32 + wi];
        sm[q][wi] = s;
    }
    if (t < 32)
        ids_s[t] = ids[b * V + wc * 32 + t];
    __syncthreads();
    if (t < 32)
        c_s[t] = sm[0][t] + sm[1][t] + sm[2][t] + sm[3][t];
    __syncthreads();
    float4 acc = make_float4(0.f, 0.f, 0.f, 0.f);
    #pragma unroll 4
    for (int i = 0; i < 32; ++i) {
        const float4* T4 = reinterpret_cast<const float4*>(emb + (size_t)ids_s[i] * HID);
        const float4 a = T4[t];
        const float  s = c_s[i];
        acc.x += s * a.x; acc.y += s * a.y; acc.z += s * a.z; acc.w += s * a.w;
    }
    float* hb = h + b * HID + t * 4;
    atomicAdd(hb + 0, acc.x);
    atomicAdd(hb + 1, acc.y);
    atomicAdd(hb + 2, acc.z);
    atomicAdd(hb + 3, acc.w);
}

// ---------------- Path B fallback (round-0 style, needs memset) -----------

__global__ void colsum_atomic_kernel(const float* __restrict__ adj, float* __restrict__ c) {
    const int b   = blockIdx.x;
    const int vc  = blockIdx.y;
    const int tid = threadIdx.x;
    const float4* adj4 = reinterpret_cast<const float4*>(adj) + (size_t)b * V * (V / 4);
    float4 acc = make_float4(0.f, 0.f, 0.f, 0.f);
    const int v0 = vc * 64;
    #pragma unroll 4
    for (int v = v0; v < v0 + 64; ++v) {
        float4 a = adj4[(size_t)v * (V / 4) + tid];
        acc.x += a.x; acc.y += a.y; acc.z += a.z; acc.w += a.w;
    }
    float* cb = c + b * V + tid * 4;
    atomicAdd(cb + 0, acc.x);
    atomicAdd(cb + 1, acc.y);
    atomicAdd(cb + 2, acc.z);
    atomicAdd(cb + 3, acc.w);
}

__global__ void gather_wsum_direct_kernel(const float* __restrict__ emb,
                                          const int* __restrict__ ids,
                                          const float* __restrict__ c,
                                          float* __restrict__ h) {
    const int b  = blockIdx.x;
    const int wc = blockIdx.y;
    const int t  = threadIdx.x;
    __shared__ float c_s[32];
    __shared__ int   ids_s[32];
    if (t < 32) {
        ids_s[t] = ids[b * V + wc * 32 + t];
        c_s[t]   = c[b * V + wc * 32 + t];
    }
    __syncthreads();
    float4 acc = make_float4(0.f, 0.f, 0.f, 0.f);
    #pragma unroll 4
    for (int i = 0; i < 32; ++i) {
        const float4* T4 = reinterpret_cast<const float4*>(emb + (size_t)ids_s[i] * HID);
        const float4 a = T4[t];
        const float  s = c_s[i];
        acc.x += s * a.x; acc.y += s * a.y; acc.z += s * a.z; acc.w += s * a.w;
    }
    float* hb = h + b * HID + t * 4;
    atomicAdd(hb + 0, acc.x);
    atomicAdd(hb + 1, acc.y);
    atomicAdd(hb + 2, acc.z);
    atomicAdd(hb + 3, acc.w);
}

// ---------------- Kernel 3 (shared) ---------------------------------------

__global__ void fc_kernel(const float* __restrict__ h,
                          const float* __restrict__ fc_w,
                          const float* __restrict__ fc_b,
                          float* __restrict__ out) {
    const int b    = blockIdx.x;
    const int wave = threadIdx.x >> 6;
    const int lane = threadIdx.x & 63;
    const int o    = blockIdx.y * 4 + wave;
    __shared__ float h_s[HID];
    for (int i = threadIdx.x; i < HID; i += 256) h_s[i] = h[b * HID + i];
    __syncthreads();
    const float* wrow = fc_w + (size_t)o * HID;
    float acc = 0.f;
    #pragma unroll
    for (int k = 0; k < HID / 64; ++k)
        acc += wrow[k * 64 + lane] * h_s[k * 64 + lane];
    #pragma unroll
    for (int off = 32; off > 0; off >>= 1)
        acc += __shfl_down(acc, off, 64);
    if (lane == 0)
        out[b * OUT + o] = fc_b[o] + acc * (1.0f / V);
}

extern "C" void kernel_launch(void* const* d_in, const int* in_sizes, int n_in,
                              void* d_out, int out_size, void* d_ws, size_t ws_size,
                              hipStream_t stream) {
    const float* emb  = (const float*)d_in[0];
    const float* adj  = (const float*)d_in[1];
    const float* fc_w = (const float*)d_in[2];
    const float* fc_b = (const float*)d_in[3];
    const int*   ids  = (const int*)d_in[4];
    float* out = (float*)d_out;

    const size_t needA = (size_t)(B * NVC * V + B * HID) * sizeof(float); // ~2.1 MB

    if (ws_size >= needA) {
        float* partial = (float*)d_ws;              // [B][NVC][V]
        float* h       = partial + B * NVC * V;     // [B][HID] (zeroed by kernel 1A)
        colsum_partial_kernel<<<dim3(B, NVC), 256, 0, stream>>>(adj, partial, h);
        gather_wsum_kernel<<<dim3(B, 32), 192, 0, stream>>>(emb, ids, partial, h);
        fc_kernel<<<dim3(B, OUT / 4), 256, 0, stream>>>(h, fc_w, fc_b, out);
    } else {
        float* c = (float*)d_ws;                    // [B][V]
        float* h = c + B * V;                       // [B][HID]
        hipMemsetAsync(d_ws, 0, (size_t)(B * V + B * HID) * sizeof(float), stream);
        colsum_atomic_kernel<<<dim3(B, NVC), 256, 0, stream>>>(adj, c);
        gather_wsum_direct_kernel<<<dim3(B, 32), 192, 0, stream>>>(emb, ids, c, h);
        fc_kernel<<<dim3(B, OUT / 4), 256, 0, stream>>>(h, fc_w, fc_b, out);
    }
}

// Round 4
// 49.424 us; speedup vs baseline: 1.3701x; 1.0931x over previous
//
#include <hip/hip_runtime.h>

#define B   32
#define V   1024
#define HID 768
#define OUT 256
#define NVC 16   // v-chunks in colsum
#define NWC 32   // w-chunks in gather

// ---------------- Path A: partial buffers, zero atomics -------------------

// Kernel 1A: partial[b][vc][w] = sum over 64 v-rows of adj[b][v][w].
// grid (B, NVC), 256 threads, float4/lane -> 4KB contiguous per iter
// (row-buffer friendly; proven pattern from rounds 0/3).
__global__ void colsum_partial_kernel(const float* __restrict__ adj,
                                      float* __restrict__ partial) {
    const int b   = blockIdx.x;
    const int vc  = blockIdx.y;
    const int tid = threadIdx.x;
    const float4* adj4 = reinterpret_cast<const float4*>(adj)
                       + (size_t)(b * V + vc * 64) * (V / 4);
    float4 acc = make_float4(0.f, 0.f, 0.f, 0.f);
    #pragma unroll 8
    for (int v = 0; v < 64; ++v) {
        float4 a = adj4[(size_t)v * (V / 4) + tid];
        acc.x += a.x; acc.y += a.y; acc.z += a.z; acc.w += a.w;
    }
    reinterpret_cast<float4*>(partial + (size_t)(b * NVC + vc) * V)[tid] = acc;
}

// Kernel 2A: hpart[b][wc][k] = sum over 32 w's of c[b][w] * emb[ids[b][w]][k],
// where c[b][w] = sum_vc partial[b][vc][w] (reduced in prologue, L2-resident).
// grid (B, NWC), 192 threads: float4/lane covers a full HID=768 row.
// Plain stores to a private slice -> no atomics anywhere.
__global__ void gather_wsum_kernel(const float* __restrict__ emb,
                                   const int* __restrict__ ids,
                                   const float* __restrict__ partial,
                                   float* __restrict__ hpart) {
    const int b  = blockIdx.x;
    const int wc = blockIdx.y;
    const int t  = threadIdx.x;         // 0..191
    __shared__ float sm[4][32];
    __shared__ float c_s[32];
    __shared__ int   ids_s[32];
    if (t < 128) {
        const int wi = t & 31, q = t >> 5;
        float s = 0.f;
        #pragma unroll
        for (int j = 0; j < 4; ++j)
            s += partial[(size_t)(b * NVC + q * 4 + j) * V + wc * 32 + wi];
        sm[q][wi] = s;
    }
    if (t < 32)
        ids_s[t] = ids[b * V + wc * 32 + t];
    __syncthreads();
    if (t < 32)
        c_s[t] = sm[0][t] + sm[1][t] + sm[2][t] + sm[3][t];
    __syncthreads();
    float4 acc = make_float4(0.f, 0.f, 0.f, 0.f);
    #pragma unroll 8
    for (int i = 0; i < 32; ++i) {
        const float4* T4 = reinterpret_cast<const float4*>(emb + (size_t)ids_s[i] * HID);
        const float4 a = T4[t];
        const float  s = c_s[i];
        acc.x += s * a.x; acc.y += s * a.y; acc.z += s * a.z; acc.w += s * a.w;
    }
    reinterpret_cast<float4*>(hpart + (size_t)(b * NWC + wc) * HID)[t] = acc;
}

// Kernel 3A: out[b][o] = fc_b[o] + (1/V) * dot(h[b][:], fc_w[o][:]),
// h reduced from 32 hpart chunks into LDS once per block.
// grid (B, 8), 256 threads: 4 waves x 8 iters = 32 outputs per block.
__global__ void fc_reduce_kernel(const float* __restrict__ hpart,
                                 const float* __restrict__ fc_w,
                                 const float* __restrict__ fc_b,
                                 float* __restrict__ out) {
    const int b  = blockIdx.x;
    const int og = blockIdx.y;
    const int t  = threadIdx.x;
    __shared__ float h_s[HID];
    {
        const float* hp = hpart + (size_t)b * NWC * HID;
        float s0 = 0.f, s1 = 0.f, s2 = 0.f;
        #pragma unroll 8
        for (int j = 0; j < NWC; ++j) {
            s0 += hp[j * HID + t];
            s1 += hp[j * HID + t + 256];
            s2 += hp[j * HID + t + 512];
        }
        h_s[t] = s0; h_s[t + 256] = s1; h_s[t + 512] = s2;
    }
    __syncthreads();
    const int wave = t >> 6, lane = t & 63;
    #pragma unroll
    for (int it = 0; it < 8; ++it) {
        const int o = og * 32 + it * 4 + wave;
        const float* wrow = fc_w + (size_t)o * HID;
        float acc = 0.f;
        #pragma unroll
        for (int k = 0; k < HID / 64; ++k)
            acc += wrow[k * 64 + lane] * h_s[k * 64 + lane];
        #pragma unroll
        for (int off = 32; off > 0; off >>= 1)
            acc += __shfl_down(acc, off, 64);
        if (lane == 0)
            out[b * OUT + o] = fc_b[o] + acc * (1.0f / V);
    }
}

// ---------------- Path B fallback (tiny ws: memset + atomics) -------------

__global__ void colsum_atomic_kernel(const float* __restrict__ adj, float* __restrict__ c) {
    const int b   = blockIdx.x;
    const int vc  = blockIdx.y;
    const int tid = threadIdx.x;
    const float4* adj4 = reinterpret_cast<const float4*>(adj) + (size_t)b * V * (V / 4);
    float4 acc = make_float4(0.f, 0.f, 0.f, 0.f);
    const int v0 = vc * 64;
    #pragma unroll 4
    for (int v = v0; v < v0 + 64; ++v) {
        float4 a = adj4[(size_t)v * (V / 4) + tid];
        acc.x += a.x; acc.y += a.y; acc.z += a.z; acc.w += a.w;
    }
    float* cb = c + b * V + tid * 4;
    atomicAdd(cb + 0, acc.x);
    atomicAdd(cb + 1, acc.y);
    atomicAdd(cb + 2, acc.z);
    atomicAdd(cb + 3, acc.w);
}

__global__ void gather_wsum_direct_kernel(const float* __restrict__ emb,
                                          const int* __restrict__ ids,
                                          const float* __restrict__ c,
                                          float* __restrict__ h) {
    const int b  = blockIdx.x;
    const int wc = blockIdx.y;
    const int t  = threadIdx.x;
    __shared__ float c_s[32];
    __shared__ int   ids_s[32];
    if (t < 32) {
        ids_s[t] = ids[b * V + wc * 32 + t];
        c_s[t]   = c[b * V + wc * 32 + t];
    }
    __syncthreads();
    float4 acc = make_float4(0.f, 0.f, 0.f, 0.f);
    #pragma unroll 4
    for (int i = 0; i < 32; ++i) {
        const float4* T4 = reinterpret_cast<const float4*>(emb + (size_t)ids_s[i] * HID);
        const float4 a = T4[t];
        const float  s = c_s[i];
        acc.x += s * a.x; acc.y += s * a.y; acc.z += s * a.z; acc.w += s * a.w;
    }
    float* hb = h + b * HID + t * 4;
    atomicAdd(hb + 0, acc.x);
    atomicAdd(hb + 1, acc.y);
    atomicAdd(hb + 2, acc.z);
    atomicAdd(hb + 3, acc.w);
}

__global__ void fc_direct_kernel(const float* __restrict__ h,
                                 const float* __restrict__ fc_w,
                                 const float* __restrict__ fc_b,
                                 float* __restrict__ out) {
    const int b    = blockIdx.x;
    const int wave = threadIdx.x >> 6;
    const int lane = threadIdx.x & 63;
    const int o    = blockIdx.y * 4 + wave;
    __shared__ float h_s[HID];
    for (int i = threadIdx.x; i < HID; i += 256) h_s[i] = h[b * HID + i];
    __syncthreads();
    const float* wrow = fc_w + (size_t)o * HID;
    float acc = 0.f;
    #pragma unroll
    for (int k = 0; k < HID / 64; ++k)
        acc += wrow[k * 64 + lane] * h_s[k * 64 + lane];
    #pragma unroll
    for (int off = 32; off > 0; off >>= 1)
        acc += __shfl_down(acc, off, 64);
    if (lane == 0)
        out[b * OUT + o] = fc_b[o] + acc * (1.0f / V);
}

extern "C" void kernel_launch(void* const* d_in, const int* in_sizes, int n_in,
                              void* d_out, int out_size, void* d_ws, size_t ws_size,
                              hipStream_t stream) {
    const float* emb  = (const float*)d_in[0];
    const float* adj  = (const float*)d_in[1];
    const float* fc_w = (const float*)d_in[2];
    const float* fc_b = (const float*)d_in[3];
    const int*   ids  = (const int*)d_in[4];
    float* out = (float*)d_out;

    const size_t needA = (size_t)(B * NVC * V + B * NWC * HID) * sizeof(float); // ~5.2 MB

    if (ws_size >= needA) {
        float* partial = (float*)d_ws;              // [B][NVC][V]    2.0 MB
        float* hpart   = partial + B * NVC * V;     // [B][NWC][HID]  3.1 MB
        colsum_partial_kernel<<<dim3(B, NVC), 256, 0, stream>>>(adj, partial);
        gather_wsum_kernel<<<dim3(B, NWC), 192, 0, stream>>>(emb, ids, partial, hpart);
        fc_reduce_kernel<<<dim3(B, 8), 256, 0, stream>>>(hpart, fc_w, fc_b, out);
    } else {
        float* c = (float*)d_ws;                    // [B][V]
        float* h = c + B * V;                       // [B][HID]
        hipMemsetAsync(d_ws, 0, (size_t)(B * V + B * HID) * sizeof(float), stream);
        colsum_atomic_kernel<<<dim3(B, NVC), 256, 0, stream>>>(adj, c);
        gather_wsum_direct_kernel<<<dim3(B, NWC), 192, 0, stream>>>(emb, ids, c, h);
        fc_direct_kernel<<<dim3(B, OUT / 4), 256, 0, stream>>>(h, fc_w, fc_b, out);
    }
}